// Round 13
// baseline (177.800 us; speedup 1.0000x reference)
//
#include <hip/hip_runtime.h>

#define NIN 64
#define NOUT 32
#define TBITS 21                 // 128^3 stride-2 lattice
#define TSIZE (1 << TBITS)
#define NB 512                   // spatial-major: 64 cells (64^3) x 8 parity classes
#define CHUNK 4096               // guides per block in prep-count/scat
#define KPT (CHUNK / 256)
#define BLKG 128                 // guides per gen_conv block = 4 waves x 2 tiles x 16

typedef __attribute__((ext_vector_type(8))) short short8;
typedef __attribute__((ext_vector_type(4))) float float4v;
typedef __attribute__((ext_vector_type(4))) unsigned short ushort4v;

__device__ __forceinline__ unsigned short bf16rne(float x) {
    unsigned u = __float_as_uint(x);
    u += 0x7fffu + ((u >> 16) & 1u);
    return (unsigned short)(u >> 16);
}

constexpr int popc8(int x) { int n = 0; for (int i = 0; i < 8; ++i) n += (x >> i) & 1; return n; }
constexpr int nth_sub(int C, int r) {
    int cnt = 0;
    for (int s = 0; s < 8; ++s)
        if ((s & ~C & 7) == 0) { if (cnt == r) return s; ++cnt; }
    return 0;
}

// SPATIAL-major bucket: all 8 classes of one 64^3 cell adjacent in bucket order
// (cross-class L2 reuse of feature rows); class = bucket & 7.
__device__ __forceinline__ int bucket_of(int4 q, int* cls) {
    int c = (q.y & 1) | ((q.z & 1) << 1) | ((q.w & 1) << 2);
    *cls = c;
    int sp = ((q.y >> 6) & 3) | (((q.z >> 6) & 3) << 2) | (((q.w >> 6) & 3) << 4);
    return (sp << 3) | c;
}

// ws (ints): [0,TSIZE) table | [TSIZE, A) sorted int2 (-1 padded) |
//   A: total[1] | pad | done[1] at A+2 | chunkhist[cblocks*NB] at A+4 |
//   wt bf16 [27][32][64] | fb bf16 [Np][64]
// prep: init table+sorted, wt/fb convert, per-chunk histogram; the LAST-finishing
// chunk block performs the bucket scan (all-thread release fences + done atomic),
// hiding the scan under prep's streaming tail (replaces the scanB dispatch).
// NOTE: table BUILD lives in scat (next dispatch) — building here races with
// the ws4 init (init block for slot lin != build block for coord i). [R12 bug]
__global__ void prep(int4* __restrict__ ws4, int n4,
                     const float* __restrict__ w, unsigned short* __restrict__ wt,
                     const float* __restrict__ f, unsigned short* __restrict__ fb,
                     int fn4,
                     const int* __restrict__ guide, int ng,
                     int* __restrict__ chunkhist, int cblocks,
                     int* __restrict__ total, int* __restrict__ done) {
    __shared__ int hist[NB];
    __shared__ int lastflag;
    int i = blockIdx.x * blockDim.x + threadIdx.x;
    if (i < n4) ws4[i] = make_int4(-1, -1, -1, -1);
    if (i < 27 * 64 * 32) {          // fp32 [27][64][32] -> bf16 [27][32][64]
        int oi = i >> 11;
        int k  = (i >> 5) & 63;
        int ch = i & 31;
        wt[oi * 2048 + ch * 64 + k] = bf16rne(w[i]);
    }
    if (i < fn4) {
        float4 v = ((const float4*)f)[i];
        ushort4v o;
        o.x = bf16rne(v.x); o.y = bf16rne(v.y);
        o.z = bf16rne(v.z); o.w = bf16rne(v.w);
        ((ushort4v*)fb)[i] = o;
    }
    int base = blockIdx.x * CHUNK;
    if (base >= ng) return;

    for (int j = threadIdx.x; j < NB; j += 256) hist[j] = 0;
    __syncthreads();
    int end = base + CHUNK; if (end > ng) end = ng;
    for (int j = base + threadIdx.x; j < end; j += 256) {
        int c;
        int b = bucket_of(((const int4*)guide)[j], &c);
        atomicAdd(&hist[b], 1);
    }
    __syncthreads();
    for (int j = threadIdx.x; j < NB; j += 256)
        chunkhist[blockIdx.x * NB + j] = hist[j];
    // release: EVERY thread fences its own chunkhist stores device-wide,
    // then thread 0 (ordered after the fences via syncthreads) bumps done.
    __threadfence();
    __syncthreads();
    if (threadIdx.x == 0) {
        int prev = atomicAdd(done, 1);
        lastflag = (prev == cblocks - 1);
    }
    __syncthreads();
    if (!lastflag) return;
    __threadfence();                             // acquire: see all chunkhists

    // ---- scan (last chunk block only; overlaps remaining prep streaming) ----
    // 256 threads, buckets (2t, 2t+1) as int2 pairs; 4-wide chunk batching.
    int2* chp = (int2*)chunkhist;                // pair index = ch*256 + t
    int t = threadIdx.x;
    int c0 = 0, c1 = 0;
    int ch = 0;
    for (; ch + 4 <= cblocks; ch += 4) {
        int2 a0 = chp[(ch + 0) * 256 + t];
        int2 a1 = chp[(ch + 1) * 256 + t];
        int2 a2 = chp[(ch + 2) * 256 + t];
        int2 a3 = chp[(ch + 3) * 256 + t];
        c0 += a0.x + a1.x + a2.x + a3.x;
        c1 += a0.y + a1.y + a2.y + a3.y;
    }
    for (; ch < cblocks; ++ch) {
        int2 a = chp[ch * 256 + t];
        c0 += a.x; c1 += a.y;
    }
    int p0 = (c0 + BLKG - 1) & ~(BLKG - 1);
    int p1 = (c1 + BLKG - 1) & ~(BLKG - 1);
    hist[t] = p0 + p1;
    __syncthreads();
    #pragma unroll
    for (int off = 1; off < 256; off <<= 1) {
        int v = hist[t];
        int u = (t >= off) ? hist[t - off] : 0;
        __syncthreads();
        hist[t] = v + u;
        __syncthreads();
    }
    int incl = hist[t];
    if (t == 255) total[0] = incl;
    int run0 = incl - (p0 + p1);                 // padded exclusive prefix
    int run1 = run0 + p0;
    ch = 0;
    for (; ch + 4 <= cblocks; ch += 4) {
        int2 a0 = chp[(ch + 0) * 256 + t];
        int2 a1 = chp[(ch + 1) * 256 + t];
        int2 a2 = chp[(ch + 2) * 256 + t];
        int2 a3 = chp[(ch + 3) * 256 + t];
        int2 w0, w1, w2, w3;
        w0.x = run0; run0 += a0.x;  w0.y = run1; run1 += a0.y;
        w1.x = run0; run0 += a1.x;  w1.y = run1; run1 += a1.y;
        w2.x = run0; run0 += a2.x;  w2.y = run1; run1 += a2.y;
        w3.x = run0; run0 += a3.x;  w3.y = run1; run1 += a3.y;
        chp[(ch + 0) * 256 + t] = w0;
        chp[(ch + 1) * 256 + t] = w1;
        chp[(ch + 2) * 256 + t] = w2;
        chp[(ch + 3) * 256 + t] = w3;
    }
    for (; ch < cblocks; ++ch) {
        int2 a = chp[ch * 256 + t];
        int2 wv;
        wv.x = run0; run0 += a.x;
        wv.y = run1; run1 += a.y;
        chp[ch * 256 + t] = wv;
    }
}

// table build (dispatch-ordered after prep's init) + chunked scatter;
// entry = {id | class<<24, x+1 | y+1<<9 | z+1<<18}
__global__ void scat(const int* __restrict__ coords, int np, int* __restrict__ table,
                     const int* __restrict__ guide, int ng,
                     const int* __restrict__ chunkhist, int2* __restrict__ sorted) {
    int gi = blockIdx.x * blockDim.x + threadIdx.x;
    if (gi < np) {
        int x = coords[gi * 4 + 1];
        int y = coords[gi * 4 + 2];
        int z = coords[gi * 4 + 3];
        table[(x >> 1) | ((y >> 1) << 7) | ((z >> 1) << 14)] = gi;
    }
    __shared__ int hist[NB];
    int t = threadIdx.x;
    int base = blockIdx.x * CHUNK;
    if (base >= ng) return;
    for (int i = t; i < NB; i += 256) hist[i] = 0;
    __syncthreads();
    int packed[KPT];                 // (bucket<<13) | lrank, or -1
    int ey[KPT];
    #pragma unroll
    for (int k = 0; k < KPT; ++k) {
        int i = base + k * 256 + t;
        packed[k] = -1;
        ey[k] = 0;
        if (i < ng) {
            int4 q = ((const int4*)guide)[i];
            int c;
            int b = bucket_of(q, &c);
            int lr = atomicAdd(&hist[b], 1);
            packed[k] = (b << 13) | lr;
            ey[k] = (q.y + 1) | ((q.z + 1) << 9) | ((q.w + 1) << 18);
        }
    }
    __syncthreads();
    for (int i = t; i < NB; i += 256)
        hist[i] = chunkhist[blockIdx.x * NB + i];   // per-chunk global base
    __syncthreads();
    #pragma unroll
    for (int k = 0; k < KPT; ++k) {
        if (packed[k] >= 0) {
            int b  = packed[k] >> 13;
            int lr = packed[k] & 8191;
            int i  = base + k * 256 + t;
            int2 e;
            e.x = i | ((b & 7) << 24);   // class = bucket & 7 (spatial-major)
            e.y = ey[k];
            sorted[hist[b] + lr] = e;
        }
    }
}

// ---------------- gen_conv helpers (class templated, rank-compacted LDS) ----------------

template<int C>
__device__ __forceinline__ void probe2t(const int* __restrict__ table, int2 s2,
                                        int quad, int* o0, int* o1) {
    int qx = (s2.y & 511) - 1;
    int qy = ((s2.y >> 9) & 511) - 1;
    int qz = ((s2.y >> 18) & 511) - 1;
    int res[2];
    #pragma unroll
    for (int r = 0; r < 2; ++r) {
        int sub = quad + r * 4;
        int offx = (C & 1) ? ((sub & 1) ? 1 : -1) : 0;
        int offy = (C & 2) ? ((sub & 2) ? 1 : -1) : 0;
        int offz = (C & 4) ? ((sub & 4) ? 1 : -1) : 0;
        int px = qx - offx, py = qy - offy, pz = qz - offz;
        bool valid = (s2.x >= 0) & ((sub & ~C & 7) == 0) &
                     ((unsigned)px < 256u) & ((unsigned)py < 256u) & ((unsigned)pz < 256u);
        int lin = (px >> 1) | ((py >> 1) << 7) | ((pz >> 1) << 14);
        int v = table[valid ? lin : 0];
        res[r] = valid ? v : -1;
    }
    *o0 = res[0]; *o1 = res[1];
}

// stage wt[oi] for admissible rank R into LDS slot (R&3), XOR swizzled
template<int C, int R, int NS>
__device__ __forceinline__ void stage_rank(const unsigned short* __restrict__ wt,
                                           unsigned short* bshr, int mm, int jj) {
    if constexpr (R < NS) {
        constexpr int SUB = nth_sub(C, R);
        constexpr int offx = (C & 1) ? ((SUB & 1) ? 1 : -1) : 0;
        constexpr int offy = (C & 2) ? ((SUB & 2) ? 1 : -1) : 0;
        constexpr int offz = (C & 4) ? ((SUB & 4) ? 1 : -1) : 0;
        constexpr int oi = (offx + 1) * 9 + (offy + 1) * 3 + (offz + 1);
        short8 v = *(const short8*)(wt + oi * 2048 + mm * 64 + jj * 8);
        *(short8*)((char*)bshr + (R & 3) * 4096 + mm * 128 + ((jj ^ (mm & 7)) << 4)) = v;
    }
}

template<int USEFB, int C, int R, int NS>
__device__ __forceinline__ void rank_load(const float* __restrict__ feats,
                                          const unsigned short* __restrict__ fb,
                                          int idx0, int idx1,
                                          unsigned long long bal0, unsigned long long bal1,
                                          int m, int quad, short8* A0, short8* A1) {
    if constexpr (R < NS) {
        constexpr int SUB = nth_sub(C, R);
        unsigned long long bal = (SUB < 4) ? bal0 : bal1;
        unsigned rowm = (unsigned)((bal >> ((SUB & 3) * 16)) & 0xffffull);
        short8 z = {0,0,0,0,0,0,0,0};
        A0[R & 3] = z; A1[R & 3] = z;
        if (rowm) {
            int h = __shfl((SUB < 4) ? idx0 : idx1, (SUB & 3) * 16 + m, 64);
            if (h >= 0) {
                if constexpr (USEFB) {
                    const unsigned short* fp = fb + (size_t)h * NIN + quad * 8;
                    A0[R & 3] = *(const short8*)fp;
                    A1[R & 3] = *(const short8*)(fp + 32);
                } else {
                    const float4* fp = (const float4*)(feats + (size_t)h * NIN + quad * 8);
                    float4 fA = fp[0], fB = fp[1];
                    const float4* fp2 = (const float4*)(feats + (size_t)h * NIN + 32 + quad * 8);
                    float4 fC = fp2[0], fD = fp2[1];
                    short8 x, y;
                    x[0] = (short)bf16rne(fA.x); x[1] = (short)bf16rne(fA.y);
                    x[2] = (short)bf16rne(fA.z); x[3] = (short)bf16rne(fA.w);
                    x[4] = (short)bf16rne(fB.x); x[5] = (short)bf16rne(fB.y);
                    x[6] = (short)bf16rne(fB.z); x[7] = (short)bf16rne(fB.w);
                    y[0] = (short)bf16rne(fC.x); y[1] = (short)bf16rne(fC.y);
                    y[2] = (short)bf16rne(fC.z); y[3] = (short)bf16rne(fC.w);
                    y[4] = (short)bf16rne(fD.x); y[5] = (short)bf16rne(fD.y);
                    y[6] = (short)bf16rne(fD.z); y[7] = (short)bf16rne(fD.w);
                    A0[R & 3] = x; A1[R & 3] = y;
                }
            }
        }
    }
}

// OPERAND-SWAPPED: mfma(W_frag, F_frag) -> acc holds out[g_m][4 consecutive ch].
template<int C, int R, int NS>
__device__ __forceinline__ void rank_mm(const unsigned short* bshr,
                                        unsigned long long bal0, unsigned long long bal1,
                                        int m, int quad, const short8* A0, const short8* A1,
                                        float4v* acc0, float4v* acc1) {
    if constexpr (R < NS) {
        constexpr int SUB = nth_sub(C, R);
        unsigned long long bal = (SUB < 4) ? bal0 : bal1;
        unsigned rowm = (unsigned)((bal >> ((SUB & 3) * 16)) & 0xffffull);
        if (rowm) {
            const char* base = (const char*)bshr + (R & 3) * 4096;
            short8 b00 = *(const short8*)(base + m * 128 + ((quad ^ (m & 7)) << 4));
            short8 b10 = *(const short8*)(base + m * 128 + (((4 + quad) ^ (m & 7)) << 4));
            short8 b01 = *(const short8*)(base + (16 + m) * 128 + ((quad ^ ((16 + m) & 7)) << 4));
            short8 b11 = *(const short8*)(base + (16 + m) * 128 + (((4 + quad) ^ ((16 + m) & 7)) << 4));
            *acc0 = __builtin_amdgcn_mfma_f32_16x16x32_bf16(b00, A0[R & 3], *acc0, 0, 0, 0);
            *acc0 = __builtin_amdgcn_mfma_f32_16x16x32_bf16(b10, A1[R & 3], *acc0, 0, 0, 0);
            *acc1 = __builtin_amdgcn_mfma_f32_16x16x32_bf16(b01, A0[R & 3], *acc1, 0, 0, 0);
            *acc1 = __builtin_amdgcn_mfma_f32_16x16x32_bf16(b11, A1[R & 3], *acc1, 0, 0, 0);
        }
    }
}

template<int USEFB, int C, int P>
__device__ __forceinline__ void phase_tile(const float* __restrict__ feats,
                                           const unsigned short* __restrict__ fb,
                                           const unsigned short* bshr,
                                           int idx0, int idx1,
                                           unsigned long long bal0, unsigned long long bal1,
                                           int m, int quad, float4v* acc0, float4v* acc1) {
    constexpr int NS = 1 << popc8(C);
    short8 A0[4], A1[4];
    rank_load<USEFB, C, P * 4 + 0, NS>(feats, fb, idx0, idx1, bal0, bal1, m, quad, A0, A1);
    rank_load<USEFB, C, P * 4 + 1, NS>(feats, fb, idx0, idx1, bal0, bal1, m, quad, A0, A1);
    rank_load<USEFB, C, P * 4 + 2, NS>(feats, fb, idx0, idx1, bal0, bal1, m, quad, A0, A1);
    rank_load<USEFB, C, P * 4 + 3, NS>(feats, fb, idx0, idx1, bal0, bal1, m, quad, A0, A1);
    rank_mm<C, P * 4 + 0, NS>(bshr, bal0, bal1, m, quad, A0, A1, acc0, acc1);
    rank_mm<C, P * 4 + 1, NS>(bshr, bal0, bal1, m, quad, A0, A1, acc0, acc1);
    rank_mm<C, P * 4 + 2, NS>(bshr, bal0, bal1, m, quad, A0, A1, acc0, acc1);
    rank_mm<C, P * 4 + 3, NS>(bshr, bal0, bal1, m, quad, A0, A1, acc0, acc1);
}

// lane (quad,m): acc0 = out[g_m][quad*4 .. +3], acc1 = out[g_m][16+quad*4 .. +3]
__device__ __forceinline__ void store_tile(int2 s2, unsigned long long eb,
                                           float4v acc0, float4v acc1,
                                           int m, int quad, const float* __restrict__ bias,
                                           float* __restrict__ out) {
    int id = (s2.x < 0) ? -1 : (s2.x & 0xffffff);
    if (id < 0) return;
    unsigned e16 = (unsigned)((eb | (eb >> 16) | (eb >> 32) | (eb >> 48)) & 0xffffull);
    bool ex = (e16 >> m) & 1;
    float4 b0 = ((const float4*)bias)[quad];
    float4 b1 = ((const float4*)bias)[4 + quad];
    float4v v0, v1;
    v0[0] = ex ? (acc0[0] + b0.x) : 0.f;
    v0[1] = ex ? (acc0[1] + b0.y) : 0.f;
    v0[2] = ex ? (acc0[2] + b0.z) : 0.f;
    v0[3] = ex ? (acc0[3] + b0.w) : 0.f;
    v1[0] = ex ? (acc1[0] + b1.x) : 0.f;
    v1[1] = ex ? (acc1[1] + b1.y) : 0.f;
    v1[2] = ex ? (acc1[2] + b1.z) : 0.f;
    v1[3] = ex ? (acc1[3] + b1.w) : 0.f;
    float* op = out + (size_t)id * NOUT;
    *(float4v*)(op + quad * 4)      = v0;
    *(float4v*)(op + 16 + quad * 4) = v1;
}

template<int USEFB, int C>
__device__ __forceinline__ void conv_class(const float* __restrict__ feats,
                                           const unsigned short* __restrict__ fb,
                                           const float* __restrict__ bias,
                                           const int* __restrict__ table,
                                           const int2* __restrict__ sorted,
                                           const unsigned short* __restrict__ wt,
                                           float* __restrict__ out,
                                           int bt0, unsigned short* bshr) {
    constexpr int NS = 1 << popc8(C);
    int tid = threadIdx.x;
    int wid = tid >> 6, lane = tid & 63;
    int m = lane & 15, quad = lane >> 4;

    int t0 = bt0 + wid * 2;
    int2 s2a = sorted[t0 * 16 + m];
    int2 s2b = sorted[t0 * 16 + 16 + m];
    int ia0, ia1, ib0, ib1;
    probe2t<C>(table, s2a, quad, &ia0, &ia1);
    probe2t<C>(table, s2b, quad, &ib0, &ib1);

    {   // stage phase 0 (ranks 0..3) into 16 KB LDS
        int mm = tid >> 3, jj = tid & 7;
        stage_rank<C, 0, NS>(wt, bshr, mm, jj);
        stage_rank<C, 1, NS>(wt, bshr, mm, jj);
        stage_rank<C, 2, NS>(wt, bshr, mm, jj);
        stage_rank<C, 3, NS>(wt, bshr, mm, jj);
    }
    __syncthreads();

    unsigned long long balA0 = __ballot(ia0 >= 0), balA1 = __ballot(ia1 >= 0);
    unsigned long long balB0 = __ballot(ib0 >= 0), balB1 = __ballot(ib1 >= 0);

    float4v aA0 = {0.f,0.f,0.f,0.f}, aA1 = {0.f,0.f,0.f,0.f};
    float4v aB0 = {0.f,0.f,0.f,0.f}, aB1 = {0.f,0.f,0.f,0.f};

    phase_tile<USEFB, C, 0>(feats, fb, bshr, ia0, ia1, balA0, balA1, m, quad, &aA0, &aA1);
    phase_tile<USEFB, C, 0>(feats, fb, bshr, ib0, ib1, balB0, balB1, m, quad, &aB0, &aB1);

    if constexpr (NS > 4) {          // class 7 only: restage ranks 4..7
        __syncthreads();
        {
            int mm = tid >> 3, jj = tid & 7;
            stage_rank<C, 4, NS>(wt, bshr, mm, jj);
            stage_rank<C, 5, NS>(wt, bshr, mm, jj);
            stage_rank<C, 6, NS>(wt, bshr, mm, jj);
            stage_rank<C, 7, NS>(wt, bshr, mm, jj);
        }
        __syncthreads();
        phase_tile<USEFB, C, 1>(feats, fb, bshr, ia0, ia1, balA0, balA1, m, quad, &aA0, &aA1);
        phase_tile<USEFB, C, 1>(feats, fb, bshr, ib0, ib1, balB0, balB1, m, quad, &aB0, &aB1);
    }

    store_tile(s2a, balA0 | balA1, aA0, aA1, m, quad, bias, out);
    store_tile(s2b, balB0 | balB1, aB0, aB1, m, quad, bias, out);
}

template<int USEFB>
__launch_bounds__(256, 6)
__global__ void gen_conv(const float* __restrict__ feats,
                         const unsigned short* __restrict__ fb,
                         const float* __restrict__ bias,
                         const int* __restrict__ table,
                         const int2* __restrict__ sorted,
                         const int* __restrict__ totalp,       // [1]
                         const unsigned short* __restrict__ wt,
                         float* __restrict__ out) {
    __shared__ unsigned short bshr[8192];                      // 16 KB

    int nwg = gridDim.x;
    int orig = blockIdx.x;
    int qd = nwg >> 3, rd = nwg & 7;
    int xc = orig & 7, ix = orig >> 3;
    int wg = (xc < rd ? xc * (qd + 1) : rd * (qd + 1) + (xc - rd) * qd) + ix;

    int g0 = wg * BLKG;
    if (g0 >= totalp[0]) return;       // uniform exit
    // block is inside one (cell,class) bucket; its first entry is always valid
    int c = (sorted[g0].x >> 24) & 7;  // uniform broadcast load
    c = __builtin_amdgcn_readfirstlane(c);
    int bt0 = wg * (BLKG / 16);

    switch (c) {
        case 0: conv_class<USEFB, 0>(feats, fb, bias, table, sorted, wt, out, bt0, bshr); break;
        case 1: conv_class<USEFB, 1>(feats, fb, bias, table, sorted, wt, out, bt0, bshr); break;
        case 2: conv_class<USEFB, 2>(feats, fb, bias, table, sorted, wt, out, bt0, bshr); break;
        case 3: conv_class<USEFB, 3>(feats, fb, bias, table, sorted, wt, out, bt0, bshr); break;
        case 4: conv_class<USEFB, 4>(feats, fb, bias, table, sorted, wt, out, bt0, bshr); break;
        case 5: conv_class<USEFB, 5>(feats, fb, bias, table, sorted, wt, out, bt0, bshr); break;
        case 6: conv_class<USEFB, 6>(feats, fb, bias, table, sorted, wt, out, bt0, bshr); break;
        case 7: conv_class<USEFB, 7>(feats, fb, bias, table, sorted, wt, out, bt0, bshr); break;
    }
}

extern "C" void kernel_launch(void* const* d_in, const int* in_sizes, int n_in,
                              void* d_out, int out_size, void* d_ws, size_t ws_size,
                              hipStream_t stream) {
    const float* feats   = (const float*)d_in[0];
    const float* weights = (const float*)d_in[1];
    const float* bias    = (const float*)d_in[2];
    const int*   coords  = (const int*)d_in[3];
    const int*   guide   = (const int*)d_in[4];
    float* out = (float*)d_out;

    int np = in_sizes[3] / 4;
    int ng = in_sizes[4] / 4;

    int cblocks = (ng + CHUNK - 1) / CHUNK;
    int* wsI = (int*)d_ws;
    int SC = (ng + NB * BLKG + 3) & ~3;      // sorted capacity (worst-case padding)
    int A = TSIZE + 2 * SC;                  // sorted is int2
    int* table     = wsI;                    // 2^21
    int2* sorted   = (int2*)(wsI + TSIZE);   // SC entries, -1 padded
    int* total     = wsI + A;                // 1
    int* done      = wsI + A + 2;            // 1
    int* chunkhist = wsI + A + 4;            // cblocks*NB (int2-aligned)
    int CH = cblocks * NB;
    unsigned short* wt = (unsigned short*)(wsI + A + 4 + CH);   // 27*32*64 bf16
    unsigned short* fb = (unsigned short*)(wsI + A + 4 + CH + 27648);
    size_t need = ((size_t)A + 4 + CH + 27648) * 4 + (size_t)np * NIN * 2;
    int usefb = (ws_size >= need) ? 1 : 0;

    hipMemsetAsync(done, 0, sizeof(int), stream);

    int n4 = A / 4;
    int fn4 = usefb ? np * (NIN / 4) : 0;
    int prep_n = n4 > fn4 ? n4 : fn4;
    if (prep_n < 27 * 64 * 32) prep_n = 27 * 64 * 32;
    int prep_blocks = (prep_n + 255) / 256;
    if (prep_blocks < cblocks) prep_blocks = cblocks;
    hipLaunchKernelGGL(prep, dim3(prep_blocks), dim3(256), 0, stream,
                       (int4*)wsI, n4, weights, wt, feats, fb, fn4,
                       guide, ng, chunkhist, cblocks, total, done);

    int sb1 = (np + 255) / 256;
    int sblocks = sb1 > cblocks ? sb1 : cblocks;
    hipLaunchKernelGGL(scat, dim3(sblocks), dim3(256), 0, stream,
                       coords, np, table, guide, ng, chunkhist, sorted);

    int maxguides = ng + NB * (BLKG - 1);
    int blocks = (maxguides + BLKG - 1) / BLKG;
    if (usefb) {
        hipLaunchKernelGGL((gen_conv<1>), dim3(blocks), dim3(256), 0, stream,
                           feats, fb, bias, table, sorted, total, wt, out);
    } else {
        hipLaunchKernelGGL((gen_conv<0>), dim3(blocks), dim3(256), 0, stream,
                           feats, fb, bias, table, sorted, total, wt, out);
    }
}

// Round 14
// 172.936 us; speedup vs baseline: 1.0281x; 1.0281x over previous
//
#include <hip/hip_runtime.h>

#define NIN 64
#define NOUT 32
#define TBITS 21                 // 128^3 stride-2 lattice
#define TSIZE (1 << TBITS)
#define NB 512                   // spatial-major: 64 cells (64^3) x 8 parity classes
#define CHUNK 4096               // guides per chunk in prep-count/scat
#define KPT (CHUNK / 256)
#define BLKG 128                 // guides per gen_conv block = 4 waves x 2 tiles x 16

typedef __attribute__((ext_vector_type(8))) short short8;
typedef __attribute__((ext_vector_type(4))) float float4v;
typedef __attribute__((ext_vector_type(4))) unsigned short ushort4v;

__device__ __forceinline__ unsigned short bf16rne(float x) {
    unsigned u = __float_as_uint(x);
    u += 0x7fffu + ((u >> 16) & 1u);
    return (unsigned short)(u >> 16);
}

constexpr int popc8(int x) { int n = 0; for (int i = 0; i < 8; ++i) n += (x >> i) & 1; return n; }
constexpr int nth_sub(int C, int r) {
    int cnt = 0;
    for (int s = 0; s < 8; ++s)
        if ((s & ~C & 7) == 0) { if (cnt == r) return s; ++cnt; }
    return 0;
}

// SPATIAL-major bucket: all 8 classes of one 64^3 cell adjacent in bucket order
// (cross-class L2 reuse of feature rows); class = bucket & 7.
__device__ __forceinline__ int bucket_of(int4 q, int* cls) {
    int c = (q.y & 1) | ((q.z & 1) << 1) | ((q.w & 1) << 2);
    *cls = c;
    int sp = ((q.y >> 6) & 3) | (((q.z >> 6) & 3) << 2) | (((q.w >> 6) & 3) << 4);
    return (sp << 3) | c;
}

// ws (ints): [0,TSIZE) table | [TSIZE, A) sorted int2 (-1 padded) |
//   A: total[4] | chunkhist[cblocks*NB] at A+4 | wt bf16 [27][32][64] | fb bf16 [Np][64]
// prep: PERSISTENT grid-stride (2048 blocks) — init table+sorted, wt/fb convert,
// per-chunk bucket histogram. Multiple elements/thread amortize wave-launch
// overhead (one-element-per-thread prep measured 45us at 1.5 TB/s: wave churn).
__global__ void prep(int4* __restrict__ ws4, int n4,
                     const float* __restrict__ w, unsigned short* __restrict__ wt,
                     const float* __restrict__ f, unsigned short* __restrict__ fb,
                     int fn4,
                     const int* __restrict__ guide, int ng, int* __restrict__ chunkhist) {
    __shared__ int hist[NB];
    int gid = blockIdx.x * 256 + threadIdx.x;
    int stride = gridDim.x * 256;
    for (int i = gid; i < n4; i += stride) ws4[i] = make_int4(-1, -1, -1, -1);
    for (int i = gid; i < 27 * 64 * 32; i += stride) {   // fp32 [27][64][32] -> bf16 [27][32][64]
        int oi = i >> 11;
        int k  = (i >> 5) & 63;
        int ch = i & 31;
        wt[oi * 2048 + ch * 64 + k] = bf16rne(w[i]);
    }
    for (int i = gid; i < fn4; i += stride) {
        float4 v = ((const float4*)f)[i];
        ushort4v o;
        o.x = bf16rne(v.x); o.y = bf16rne(v.y);
        o.z = bf16rne(v.z); o.w = bf16rne(v.w);
        ((ushort4v*)fb)[i] = o;
    }
    int cblocks = (ng + CHUNK - 1) / CHUNK;
    for (int ch = blockIdx.x; ch < cblocks; ch += gridDim.x) {
        for (int j = threadIdx.x; j < NB; j += 256) hist[j] = 0;
        __syncthreads();
        int base = ch * CHUNK;
        int end = base + CHUNK; if (end > ng) end = ng;
        for (int j = base + threadIdx.x; j < end; j += 256) {
            int c;
            int b = bucket_of(((const int4*)guide)[j], &c);
            atomicAdd(&hist[b], 1);
        }
        __syncthreads();
        for (int j = threadIdx.x; j < NB; j += 256)
            chunkhist[ch * NB + j] = hist[j];
        __syncthreads();
    }
}

// single block, 512 threads (1 bucket each): aggregate chunk hists, BLKG-pad
// prefix over buckets, rewrite chunkhist in-place as per-chunk write bases.
// Chunk loops are 8-wide batched so memory latency is amortized.
__global__ void scanB(int* __restrict__ chunkhist, int cblocks, int* __restrict__ total) {
    __shared__ int ps[NB];
    int t = threadIdx.x;
    int cnt = 0;
    int ch = 0;
    for (; ch + 8 <= cblocks; ch += 8) {
        int v0 = chunkhist[(ch + 0) * NB + t];
        int v1 = chunkhist[(ch + 1) * NB + t];
        int v2 = chunkhist[(ch + 2) * NB + t];
        int v3 = chunkhist[(ch + 3) * NB + t];
        int v4 = chunkhist[(ch + 4) * NB + t];
        int v5 = chunkhist[(ch + 5) * NB + t];
        int v6 = chunkhist[(ch + 6) * NB + t];
        int v7 = chunkhist[(ch + 7) * NB + t];
        cnt += v0 + v1 + v2 + v3 + v4 + v5 + v6 + v7;
    }
    for (; ch < cblocks; ++ch) cnt += chunkhist[ch * NB + t];

    int padded = (cnt + BLKG - 1) & ~(BLKG - 1);
    ps[t] = padded;
    __syncthreads();
    #pragma unroll
    for (int off = 1; off < NB; off <<= 1) {
        int v = ps[t];
        int u = (t >= off) ? ps[t - off] : 0;
        __syncthreads();
        ps[t] = v + u;
        __syncthreads();
    }
    if (t == NB - 1) total[0] = ps[NB - 1];
    int run = ps[t] - padded;            // exclusive padded prefix = bucket base
    ch = 0;
    for (; ch + 8 <= cblocks; ch += 8) {
        int v0 = chunkhist[(ch + 0) * NB + t];
        int v1 = chunkhist[(ch + 1) * NB + t];
        int v2 = chunkhist[(ch + 2) * NB + t];
        int v3 = chunkhist[(ch + 3) * NB + t];
        int v4 = chunkhist[(ch + 4) * NB + t];
        int v5 = chunkhist[(ch + 5) * NB + t];
        int v6 = chunkhist[(ch + 6) * NB + t];
        int v7 = chunkhist[(ch + 7) * NB + t];
        int w0 = run; run += v0;
        int w1 = run; run += v1;
        int w2 = run; run += v2;
        int w3 = run; run += v3;
        int w4 = run; run += v4;
        int w5 = run; run += v5;
        int w6 = run; run += v6;
        int w7 = run; run += v7;
        chunkhist[(ch + 0) * NB + t] = w0;
        chunkhist[(ch + 1) * NB + t] = w1;
        chunkhist[(ch + 2) * NB + t] = w2;
        chunkhist[(ch + 3) * NB + t] = w3;
        chunkhist[(ch + 4) * NB + t] = w4;
        chunkhist[(ch + 5) * NB + t] = w5;
        chunkhist[(ch + 6) * NB + t] = w6;
        chunkhist[(ch + 7) * NB + t] = w7;
    }
    for (; ch < cblocks; ++ch) {
        int v = chunkhist[ch * NB + t];
        chunkhist[ch * NB + t] = run;
        run += v;
    }
}

// PERSISTENT grid-stride (1024 blocks): table build (ordered after prep's init)
// + chunked scatter; entry = {id | class<<24, x+1 | y+1<<9 | z+1<<18}
__global__ void scat(const int* __restrict__ coords, int np, int* __restrict__ table,
                     const int* __restrict__ guide, int ng,
                     const int* __restrict__ chunkhist, int2* __restrict__ sorted) {
    __shared__ int hist[NB];
    int gid = blockIdx.x * 256 + threadIdx.x;
    int stride = gridDim.x * 256;
    for (int i = gid; i < np; i += stride) {
        int x = coords[i * 4 + 1];
        int y = coords[i * 4 + 2];
        int z = coords[i * 4 + 3];
        table[(x >> 1) | ((y >> 1) << 7) | ((z >> 1) << 14)] = i;
    }
    int t = threadIdx.x;
    int cblocks = (ng + CHUNK - 1) / CHUNK;
    for (int ch = blockIdx.x; ch < cblocks; ch += gridDim.x) {
        for (int i = t; i < NB; i += 256) hist[i] = 0;
        __syncthreads();
        int base = ch * CHUNK;
        int packed[KPT];             // (bucket<<13) | lrank, or -1
        int ey[KPT];
        #pragma unroll
        for (int k = 0; k < KPT; ++k) {
            int i = base + k * 256 + t;
            packed[k] = -1;
            ey[k] = 0;
            if (i < ng) {
                int4 q = ((const int4*)guide)[i];
                int c;
                int b = bucket_of(q, &c);
                int lr = atomicAdd(&hist[b], 1);
                packed[k] = (b << 13) | lr;
                ey[k] = (q.y + 1) | ((q.z + 1) << 9) | ((q.w + 1) << 18);
            }
        }
        __syncthreads();
        for (int i = t; i < NB; i += 256)
            hist[i] = chunkhist[ch * NB + i];   // per-chunk global base
        __syncthreads();
        #pragma unroll
        for (int k = 0; k < KPT; ++k) {
            if (packed[k] >= 0) {
                int b  = packed[k] >> 13;
                int lr = packed[k] & 8191;
                int i  = base + k * 256 + t;
                int2 e;
                e.x = i | ((b & 7) << 24);   // class = bucket & 7 (spatial-major)
                e.y = ey[k];
                sorted[hist[b] + lr] = e;
            }
        }
        __syncthreads();
    }
}

// ---------------- gen_conv helpers (class templated, rank-compacted LDS) ----------------

template<int C>
__device__ __forceinline__ void probe2t(const int* __restrict__ table, int2 s2,
                                        int quad, int* o0, int* o1) {
    int qx = (s2.y & 511) - 1;
    int qy = ((s2.y >> 9) & 511) - 1;
    int qz = ((s2.y >> 18) & 511) - 1;
    int res[2];
    #pragma unroll
    for (int r = 0; r < 2; ++r) {
        int sub = quad + r * 4;
        int offx = (C & 1) ? ((sub & 1) ? 1 : -1) : 0;
        int offy = (C & 2) ? ((sub & 2) ? 1 : -1) : 0;
        int offz = (C & 4) ? ((sub & 4) ? 1 : -1) : 0;
        int px = qx - offx, py = qy - offy, pz = qz - offz;
        bool valid = (s2.x >= 0) & ((sub & ~C & 7) == 0) &
                     ((unsigned)px < 256u) & ((unsigned)py < 256u) & ((unsigned)pz < 256u);
        int lin = (px >> 1) | ((py >> 1) << 7) | ((pz >> 1) << 14);
        int v = table[valid ? lin : 0];
        res[r] = valid ? v : -1;
    }
    *o0 = res[0]; *o1 = res[1];
}

// stage wt[oi] for admissible rank R into LDS slot (R&3), XOR swizzled
template<int C, int R, int NS>
__device__ __forceinline__ void stage_rank(const unsigned short* __restrict__ wt,
                                           unsigned short* bshr, int mm, int jj) {
    if constexpr (R < NS) {
        constexpr int SUB = nth_sub(C, R);
        constexpr int offx = (C & 1) ? ((SUB & 1) ? 1 : -1) : 0;
        constexpr int offy = (C & 2) ? ((SUB & 2) ? 1 : -1) : 0;
        constexpr int offz = (C & 4) ? ((SUB & 4) ? 1 : -1) : 0;
        constexpr int oi = (offx + 1) * 9 + (offy + 1) * 3 + (offz + 1);
        short8 v = *(const short8*)(wt + oi * 2048 + mm * 64 + jj * 8);
        *(short8*)((char*)bshr + (R & 3) * 4096 + mm * 128 + ((jj ^ (mm & 7)) << 4)) = v;
    }
}

template<int USEFB, int C, int R, int NS>
__device__ __forceinline__ void rank_load(const float* __restrict__ feats,
                                          const unsigned short* __restrict__ fb,
                                          int idx0, int idx1,
                                          unsigned long long bal0, unsigned long long bal1,
                                          int m, int quad, short8* A0, short8* A1) {
    if constexpr (R < NS) {
        constexpr int SUB = nth_sub(C, R);
        unsigned long long bal = (SUB < 4) ? bal0 : bal1;
        unsigned rowm = (unsigned)((bal >> ((SUB & 3) * 16)) & 0xffffull);
        short8 z = {0,0,0,0,0,0,0,0};
        A0[R & 3] = z; A1[R & 3] = z;
        if (rowm) {
            int h = __shfl((SUB < 4) ? idx0 : idx1, (SUB & 3) * 16 + m, 64);
            if (h >= 0) {
                if constexpr (USEFB) {
                    const unsigned short* fp = fb + (size_t)h * NIN + quad * 8;
                    A0[R & 3] = *(const short8*)fp;
                    A1[R & 3] = *(const short8*)(fp + 32);
                } else {
                    const float4* fp = (const float4*)(feats + (size_t)h * NIN + quad * 8);
                    float4 fA = fp[0], fB = fp[1];
                    const float4* fp2 = (const float4*)(feats + (size_t)h * NIN + 32 + quad * 8);
                    float4 fC = fp2[0], fD = fp2[1];
                    short8 x, y;
                    x[0] = (short)bf16rne(fA.x); x[1] = (short)bf16rne(fA.y);
                    x[2] = (short)bf16rne(fA.z); x[3] = (short)bf16rne(fA.w);
                    x[4] = (short)bf16rne(fB.x); x[5] = (short)bf16rne(fB.y);
                    x[6] = (short)bf16rne(fB.z); x[7] = (short)bf16rne(fB.w);
                    y[0] = (short)bf16rne(fC.x); y[1] = (short)bf16rne(fC.y);
                    y[2] = (short)bf16rne(fC.z); y[3] = (short)bf16rne(fC.w);
                    y[4] = (short)bf16rne(fD.x); y[5] = (short)bf16rne(fD.y);
                    y[6] = (short)bf16rne(fD.z); y[7] = (short)bf16rne(fD.w);
                    A0[R & 3] = x; A1[R & 3] = y;
                }
            }
        }
    }
}

// OPERAND-SWAPPED: mfma(W_frag, F_frag) -> acc holds out[g_m][4 consecutive ch].
template<int C, int R, int NS>
__device__ __forceinline__ void rank_mm(const unsigned short* bshr,
                                        unsigned long long bal0, unsigned long long bal1,
                                        int m, int quad, const short8* A0, const short8* A1,
                                        float4v* acc0, float4v* acc1) {
    if constexpr (R < NS) {
        constexpr int SUB = nth_sub(C, R);
        unsigned long long bal = (SUB < 4) ? bal0 : bal1;
        unsigned rowm = (unsigned)((bal >> ((SUB & 3) * 16)) & 0xffffull);
        if (rowm) {
            const char* base = (const char*)bshr + (R & 3) * 4096;
            short8 b00 = *(const short8*)(base + m * 128 + ((quad ^ (m & 7)) << 4));
            short8 b10 = *(const short8*)(base + m * 128 + (((4 + quad) ^ (m & 7)) << 4));
            short8 b01 = *(const short8*)(base + (16 + m) * 128 + ((quad ^ ((16 + m) & 7)) << 4));
            short8 b11 = *(const short8*)(base + (16 + m) * 128 + (((4 + quad) ^ ((16 + m) & 7)) << 4));
            *acc0 = __builtin_amdgcn_mfma_f32_16x16x32_bf16(b00, A0[R & 3], *acc0, 0, 0, 0);
            *acc0 = __builtin_amdgcn_mfma_f32_16x16x32_bf16(b10, A1[R & 3], *acc0, 0, 0, 0);
            *acc1 = __builtin_amdgcn_mfma_f32_16x16x32_bf16(b01, A0[R & 3], *acc1, 0, 0, 0);
            *acc1 = __builtin_amdgcn_mfma_f32_16x16x32_bf16(b11, A1[R & 3], *acc1, 0, 0, 0);
        }
    }
}

template<int USEFB, int C, int P>
__device__ __forceinline__ void phase_tile(const float* __restrict__ feats,
                                           const unsigned short* __restrict__ fb,
                                           const unsigned short* bshr,
                                           int idx0, int idx1,
                                           unsigned long long bal0, unsigned long long bal1,
                                           int m, int quad, float4v* acc0, float4v* acc1) {
    constexpr int NS = 1 << popc8(C);
    short8 A0[4], A1[4];
    rank_load<USEFB, C, P * 4 + 0, NS>(feats, fb, idx0, idx1, bal0, bal1, m, quad, A0, A1);
    rank_load<USEFB, C, P * 4 + 1, NS>(feats, fb, idx0, idx1, bal0, bal1, m, quad, A0, A1);
    rank_load<USEFB, C, P * 4 + 2, NS>(feats, fb, idx0, idx1, bal0, bal1, m, quad, A0, A1);
    rank_load<USEFB, C, P * 4 + 3, NS>(feats, fb, idx0, idx1, bal0, bal1, m, quad, A0, A1);
    rank_mm<C, P * 4 + 0, NS>(bshr, bal0, bal1, m, quad, A0, A1, acc0, acc1);
    rank_mm<C, P * 4 + 1, NS>(bshr, bal0, bal1, m, quad, A0, A1, acc0, acc1);
    rank_mm<C, P * 4 + 2, NS>(bshr, bal0, bal1, m, quad, A0, A1, acc0, acc1);
    rank_mm<C, P * 4 + 3, NS>(bshr, bal0, bal1, m, quad, A0, A1, acc0, acc1);
}

// lane (quad,m): acc0 = out[g_m][quad*4 .. +3], acc1 = out[g_m][16+quad*4 .. +3]
__device__ __forceinline__ void store_tile(int2 s2, unsigned long long eb,
                                           float4v acc0, float4v acc1,
                                           int m, int quad, const float* __restrict__ bias,
                                           float* __restrict__ out) {
    int id = (s2.x < 0) ? -1 : (s2.x & 0xffffff);
    if (id < 0) return;
    unsigned e16 = (unsigned)((eb | (eb >> 16) | (eb >> 32) | (eb >> 48)) & 0xffffull);
    bool ex = (e16 >> m) & 1;
    float4 b0 = ((const float4*)bias)[quad];
    float4 b1 = ((const float4*)bias)[4 + quad];
    float4v v0, v1;
    v0[0] = ex ? (acc0[0] + b0.x) : 0.f;
    v0[1] = ex ? (acc0[1] + b0.y) : 0.f;
    v0[2] = ex ? (acc0[2] + b0.z) : 0.f;
    v0[3] = ex ? (acc0[3] + b0.w) : 0.f;
    v1[0] = ex ? (acc1[0] + b1.x) : 0.f;
    v1[1] = ex ? (acc1[1] + b1.y) : 0.f;
    v1[2] = ex ? (acc1[2] + b1.z) : 0.f;
    v1[3] = ex ? (acc1[3] + b1.w) : 0.f;
    float* op = out + (size_t)id * NOUT;
    *(float4v*)(op + quad * 4)      = v0;
    *(float4v*)(op + 16 + quad * 4) = v1;
}

template<int USEFB, int C>
__device__ __forceinline__ void conv_class(const float* __restrict__ feats,
                                           const unsigned short* __restrict__ fb,
                                           const float* __restrict__ bias,
                                           const int* __restrict__ table,
                                           const int2* __restrict__ sorted,
                                           const unsigned short* __restrict__ wt,
                                           float* __restrict__ out,
                                           int bt0, unsigned short* bshr) {
    constexpr int NS = 1 << popc8(C);
    int tid = threadIdx.x;
    int wid = tid >> 6, lane = tid & 63;
    int m = lane & 15, quad = lane >> 4;

    int t0 = bt0 + wid * 2;
    int2 s2a = sorted[t0 * 16 + m];
    int2 s2b = sorted[t0 * 16 + 16 + m];
    int ia0, ia1, ib0, ib1;
    probe2t<C>(table, s2a, quad, &ia0, &ia1);
    probe2t<C>(table, s2b, quad, &ib0, &ib1);

    {   // stage phase 0 (ranks 0..3) into 16 KB LDS
        int mm = tid >> 3, jj = tid & 7;
        stage_rank<C, 0, NS>(wt, bshr, mm, jj);
        stage_rank<C, 1, NS>(wt, bshr, mm, jj);
        stage_rank<C, 2, NS>(wt, bshr, mm, jj);
        stage_rank<C, 3, NS>(wt, bshr, mm, jj);
    }
    __syncthreads();

    unsigned long long balA0 = __ballot(ia0 >= 0), balA1 = __ballot(ia1 >= 0);
    unsigned long long balB0 = __ballot(ib0 >= 0), balB1 = __ballot(ib1 >= 0);

    float4v aA0 = {0.f,0.f,0.f,0.f}, aA1 = {0.f,0.f,0.f,0.f};
    float4v aB0 = {0.f,0.f,0.f,0.f}, aB1 = {0.f,0.f,0.f,0.f};

    phase_tile<USEFB, C, 0>(feats, fb, bshr, ia0, ia1, balA0, balA1, m, quad, &aA0, &aA1);
    phase_tile<USEFB, C, 0>(feats, fb, bshr, ib0, ib1, balB0, balB1, m, quad, &aB0, &aB1);

    if constexpr (NS > 4) {          // class 7 only: restage ranks 4..7
        __syncthreads();
        {
            int mm = tid >> 3, jj = tid & 7;
            stage_rank<C, 4, NS>(wt, bshr, mm, jj);
            stage_rank<C, 5, NS>(wt, bshr, mm, jj);
            stage_rank<C, 6, NS>(wt, bshr, mm, jj);
            stage_rank<C, 7, NS>(wt, bshr, mm, jj);
        }
        __syncthreads();
        phase_tile<USEFB, C, 1>(feats, fb, bshr, ia0, ia1, balA0, balA1, m, quad, &aA0, &aA1);
        phase_tile<USEFB, C, 1>(feats, fb, bshr, ib0, ib1, balB0, balB1, m, quad, &aB0, &aB1);
    }

    store_tile(s2a, balA0 | balA1, aA0, aA1, m, quad, bias, out);
    store_tile(s2b, balB0 | balB1, aB0, aB1, m, quad, bias, out);
}

template<int USEFB>
__launch_bounds__(256, 6)
__global__ void gen_conv(const float* __restrict__ feats,
                         const unsigned short* __restrict__ fb,
                         const float* __restrict__ bias,
                         const int* __restrict__ table,
                         const int2* __restrict__ sorted,
                         const int* __restrict__ totalp,       // [1]
                         const unsigned short* __restrict__ wt,
                         float* __restrict__ out) {
    __shared__ unsigned short bshr[8192];                      // 16 KB

    int nwg = gridDim.x;
    int orig = blockIdx.x;
    int qd = nwg >> 3, rd = nwg & 7;
    int xc = orig & 7, ix = orig >> 3;
    int wg = (xc < rd ? xc * (qd + 1) : rd * (qd + 1) + (xc - rd) * qd) + ix;

    int g0 = wg * BLKG;
    if (g0 >= totalp[0]) return;       // uniform exit
    // block is inside one (cell,class) bucket; its first entry is always valid
    int c = (sorted[g0].x >> 24) & 7;  // uniform broadcast load
    c = __builtin_amdgcn_readfirstlane(c);
    int bt0 = wg * (BLKG / 16);

    switch (c) {
        case 0: conv_class<USEFB, 0>(feats, fb, bias, table, sorted, wt, out, bt0, bshr); break;
        case 1: conv_class<USEFB, 1>(feats, fb, bias, table, sorted, wt, out, bt0, bshr); break;
        case 2: conv_class<USEFB, 2>(feats, fb, bias, table, sorted, wt, out, bt0, bshr); break;
        case 3: conv_class<USEFB, 3>(feats, fb, bias, table, sorted, wt, out, bt0, bshr); break;
        case 4: conv_class<USEFB, 4>(feats, fb, bias, table, sorted, wt, out, bt0, bshr); break;
        case 5: conv_class<USEFB, 5>(feats, fb, bias, table, sorted, wt, out, bt0, bshr); break;
        case 6: conv_class<USEFB, 6>(feats, fb, bias, table, sorted, wt, out, bt0, bshr); break;
        case 7: conv_class<USEFB, 7>(feats, fb, bias, table, sorted, wt, out, bt0, bshr); break;
    }
}

extern "C" void kernel_launch(void* const* d_in, const int* in_sizes, int n_in,
                              void* d_out, int out_size, void* d_ws, size_t ws_size,
                              hipStream_t stream) {
    const float* feats   = (const float*)d_in[0];
    const float* weights = (const float*)d_in[1];
    const float* bias    = (const float*)d_in[2];
    const int*   coords  = (const int*)d_in[3];
    const int*   guide   = (const int*)d_in[4];
    float* out = (float*)d_out;

    int np = in_sizes[3] / 4;
    int ng = in_sizes[4] / 4;

    int cblocks = (ng + CHUNK - 1) / CHUNK;
    int* wsI = (int*)d_ws;
    int SC = (ng + NB * BLKG + 3) & ~3;      // sorted capacity (worst-case padding)
    int A = TSIZE + 2 * SC;                  // sorted is int2
    int* table     = wsI;                    // 2^21
    int2* sorted   = (int2*)(wsI + TSIZE);   // SC entries, -1 padded
    int* total     = wsI + A;                // 1 (+3 pad)
    int* chunkhist = wsI + A + 4;            // cblocks*NB
    int CH = cblocks * NB;
    unsigned short* wt = (unsigned short*)(wsI + A + 4 + CH);   // 27*32*64 bf16
    unsigned short* fb = (unsigned short*)(wsI + A + 4 + CH + 27648);
    size_t need = ((size_t)A + 4 + CH + 27648) * 4 + (size_t)np * NIN * 2;
    int usefb = (ws_size >= need) ? 1 : 0;

    int n4 = A / 4;
    int fn4 = usefb ? np * (NIN / 4) : 0;

    int prep_grid = 2048;
    if (prep_grid < cblocks) prep_grid = cblocks;
    hipLaunchKernelGGL(prep, dim3(prep_grid), dim3(256), 0, stream,
                       (int4*)wsI, n4, weights, wt, feats, fb, fn4,
                       guide, ng, chunkhist);

    hipLaunchKernelGGL(scanB, dim3(1), dim3(NB), 0, stream, chunkhist, cblocks, total);

    int scat_grid = 1024;
    if (scat_grid < cblocks) scat_grid = cblocks;
    hipLaunchKernelGGL(scat, dim3(scat_grid), dim3(256), 0, stream,
                       coords, np, table, guide, ng, chunkhist, sorted);

    int maxguides = ng + NB * (BLKG - 1);
    int blocks = (maxguides + BLKG - 1) / BLKG;
    if (usefb) {
        hipLaunchKernelGGL((gen_conv<1>), dim3(blocks), dim3(256), 0, stream,
                           feats, fb, bias, table, sorted, total, wt, out);
    } else {
        hipLaunchKernelGGL((gen_conv<0>), dim3(blocks), dim3(256), 0, stream,
                           feats, fb, bias, table, sorted, total, wt, out);
    }
}

// Round 15
// 165.699 us; speedup vs baseline: 1.0730x; 1.0437x over previous
//
#include <hip/hip_runtime.h>

#define NIN 64
#define NOUT 32
#define TBITS 21                 // 128^3 stride-2 lattice
#define TSIZE (1 << TBITS)
#define NB 512                   // spatial-major: 64 cells (64^3) x 8 parity classes
#define CHUNK 4096               // guides per block in prep-count/scat
#define KPT (CHUNK / 256)
#define BLKG 128                 // guides per gen_conv block = 4 waves x 2 tiles x 16

typedef __attribute__((ext_vector_type(8))) short short8;
typedef __attribute__((ext_vector_type(4))) float float4v;
typedef __attribute__((ext_vector_type(4))) unsigned short ushort4v;

__device__ __forceinline__ unsigned short bf16rne(float x) {
    unsigned u = __float_as_uint(x);
    u += 0x7fffu + ((u >> 16) & 1u);
    return (unsigned short)(u >> 16);
}

constexpr int popc8(int x) { int n = 0; for (int i = 0; i < 8; ++i) n += (x >> i) & 1; return n; }
constexpr int nth_sub(int C, int r) {
    int cnt = 0;
    for (int s = 0; s < 8; ++s)
        if ((s & ~C & 7) == 0) { if (cnt == r) return s; ++cnt; }
    return 0;
}

// SPATIAL-major bucket: all 8 classes of one 64^3 cell adjacent in bucket order
// (cross-class L2 reuse of feature rows); class = bucket & 7.
__device__ __forceinline__ int bucket_of(int4 q, int* cls) {
    int c = (q.y & 1) | ((q.z & 1) << 1) | ((q.w & 1) << 2);
    *cls = c;
    int sp = ((q.y >> 6) & 3) | (((q.z >> 6) & 3) << 2) | (((q.w >> 6) & 3) << 4);
    return (sp << 3) | c;
}

// ws (ints): [0,TSIZE) table | [TSIZE, A) sorted int2 (-1 padded) |
//   A: total[4] | chunkhist[cblocks*NB] at A+4 | wt bf16 [27][32][64] | fb bf16 [Np][64]
// prep: init table+sorted, wt/fb convert, per-chunk bucket histogram (no atomics)
__global__ void prep(int4* __restrict__ ws4, int n4,
                     const float* __restrict__ w, unsigned short* __restrict__ wt,
                     const float* __restrict__ f, unsigned short* __restrict__ fb,
                     int fn4,
                     const int* __restrict__ guide, int ng, int* __restrict__ chunkhist) {
    __shared__ int hist[NB];
    int i = blockIdx.x * blockDim.x + threadIdx.x;
    if (i < n4) ws4[i] = make_int4(-1, -1, -1, -1);
    if (i < 27 * 64 * 32) {          // fp32 [27][64][32] -> bf16 [27][32][64]
        int oi = i >> 11;
        int k  = (i >> 5) & 63;
        int ch = i & 31;
        wt[oi * 2048 + ch * 64 + k] = bf16rne(w[i]);
    }
    if (i < fn4) {
        float4 v = ((const float4*)f)[i];
        ushort4v o;
        o.x = bf16rne(v.x); o.y = bf16rne(v.y);
        o.z = bf16rne(v.z); o.w = bf16rne(v.w);
        ((ushort4v*)fb)[i] = o;
    }
    int base = blockIdx.x * CHUNK;
    if (base < ng) {
        for (int j = threadIdx.x; j < NB; j += 256) hist[j] = 0;
        __syncthreads();
        int end = base + CHUNK; if (end > ng) end = ng;
        for (int j = base + threadIdx.x; j < end; j += 256) {
            int c;
            int b = bucket_of(((const int4*)guide)[j], &c);
            atomicAdd(&hist[b], 1);
        }
        __syncthreads();
        for (int j = threadIdx.x; j < NB; j += 256)
            chunkhist[blockIdx.x * NB + j] = hist[j];
    }
}

// single block, 512 threads (1 bucket each): aggregate chunk hists, BLKG-pad
// prefix over buckets, rewrite chunkhist in-place as per-chunk write bases.
// Chunk loops are 8-wide batched so memory latency is amortized.
__global__ void scanB(int* __restrict__ chunkhist, int cblocks, int* __restrict__ total) {
    __shared__ int ps[NB];
    int t = threadIdx.x;
    int cnt = 0;
    int ch = 0;
    for (; ch + 8 <= cblocks; ch += 8) {
        int v0 = chunkhist[(ch + 0) * NB + t];
        int v1 = chunkhist[(ch + 1) * NB + t];
        int v2 = chunkhist[(ch + 2) * NB + t];
        int v3 = chunkhist[(ch + 3) * NB + t];
        int v4 = chunkhist[(ch + 4) * NB + t];
        int v5 = chunkhist[(ch + 5) * NB + t];
        int v6 = chunkhist[(ch + 6) * NB + t];
        int v7 = chunkhist[(ch + 7) * NB + t];
        cnt += v0 + v1 + v2 + v3 + v4 + v5 + v6 + v7;
    }
    for (; ch < cblocks; ++ch) cnt += chunkhist[ch * NB + t];

    int padded = (cnt + BLKG - 1) & ~(BLKG - 1);
    ps[t] = padded;
    __syncthreads();
    #pragma unroll
    for (int off = 1; off < NB; off <<= 1) {
        int v = ps[t];
        int u = (t >= off) ? ps[t - off] : 0;
        __syncthreads();
        ps[t] = v + u;
        __syncthreads();
    }
    if (t == NB - 1) total[0] = ps[NB - 1];
    int run = ps[t] - padded;            // exclusive padded prefix = bucket base
    ch = 0;
    for (; ch + 8 <= cblocks; ch += 8) {
        int v0 = chunkhist[(ch + 0) * NB + t];
        int v1 = chunkhist[(ch + 1) * NB + t];
        int v2 = chunkhist[(ch + 2) * NB + t];
        int v3 = chunkhist[(ch + 3) * NB + t];
        int v4 = chunkhist[(ch + 4) * NB + t];
        int v5 = chunkhist[(ch + 5) * NB + t];
        int v6 = chunkhist[(ch + 6) * NB + t];
        int v7 = chunkhist[(ch + 7) * NB + t];
        int w0 = run; run += v0;
        int w1 = run; run += v1;
        int w2 = run; run += v2;
        int w3 = run; run += v3;
        int w4 = run; run += v4;
        int w5 = run; run += v5;
        int w6 = run; run += v6;
        int w7 = run; run += v7;
        chunkhist[(ch + 0) * NB + t] = w0;
        chunkhist[(ch + 1) * NB + t] = w1;
        chunkhist[(ch + 2) * NB + t] = w2;
        chunkhist[(ch + 3) * NB + t] = w3;
        chunkhist[(ch + 4) * NB + t] = w4;
        chunkhist[(ch + 5) * NB + t] = w5;
        chunkhist[(ch + 6) * NB + t] = w6;
        chunkhist[(ch + 7) * NB + t] = w7;
    }
    for (; ch < cblocks; ++ch) {
        int v = chunkhist[ch * NB + t];
        chunkhist[ch * NB + t] = run;
        run += v;
    }
}

// table build + chunked scatter (no global atomics);
// entry = {id | class<<24, x+1 | y+1<<9 | z+1<<18}
__global__ void scat(const int* __restrict__ coords, int np, int* __restrict__ table,
                     const int* __restrict__ guide, int ng,
                     const int* __restrict__ chunkhist, int2* __restrict__ sorted) {
    int gi = blockIdx.x * blockDim.x + threadIdx.x;
    if (gi < np) {
        int x = coords[gi * 4 + 1];
        int y = coords[gi * 4 + 2];
        int z = coords[gi * 4 + 3];
        table[(x >> 1) | ((y >> 1) << 7) | ((z >> 1) << 14)] = gi;
    }
    __shared__ int hist[NB];
    int t = threadIdx.x;
    int base = blockIdx.x * CHUNK;
    if (base >= ng) return;
    for (int i = t; i < NB; i += 256) hist[i] = 0;
    __syncthreads();
    int packed[KPT];                 // (bucket<<13) | lrank, or -1
    int ey[KPT];
    #pragma unroll
    for (int k = 0; k < KPT; ++k) {
        int i = base + k * 256 + t;
        packed[k] = -1;
        ey[k] = 0;
        if (i < ng) {
            int4 q = ((const int4*)guide)[i];
            int c;
            int b = bucket_of(q, &c);
            int lr = atomicAdd(&hist[b], 1);
            packed[k] = (b << 13) | lr;
            ey[k] = (q.y + 1) | ((q.z + 1) << 9) | ((q.w + 1) << 18);
        }
    }
    __syncthreads();
    for (int i = t; i < NB; i += 256)
        hist[i] = chunkhist[blockIdx.x * NB + i];   // per-chunk global base
    __syncthreads();
    #pragma unroll
    for (int k = 0; k < KPT; ++k) {
        if (packed[k] >= 0) {
            int b  = packed[k] >> 13;
            int lr = packed[k] & 8191;
            int i  = base + k * 256 + t;
            int2 e;
            e.x = i | ((b & 7) << 24);   // class = bucket & 7 (spatial-major)
            e.y = ey[k];
            sorted[hist[b] + lr] = e;
        }
    }
}

// ---------------- gen_conv helpers (class templated, rank-compacted LDS) ----------------

template<int C>
__device__ __forceinline__ void probe2t(const int* __restrict__ table, int2 s2,
                                        int quad, int* o0, int* o1) {
    int qx = (s2.y & 511) - 1;
    int qy = ((s2.y >> 9) & 511) - 1;
    int qz = ((s2.y >> 18) & 511) - 1;
    int res[2];
    #pragma unroll
    for (int r = 0; r < 2; ++r) {
        int sub = quad + r * 4;
        int offx = (C & 1) ? ((sub & 1) ? 1 : -1) : 0;
        int offy = (C & 2) ? ((sub & 2) ? 1 : -1) : 0;
        int offz = (C & 4) ? ((sub & 4) ? 1 : -1) : 0;
        int px = qx - offx, py = qy - offy, pz = qz - offz;
        bool valid = (s2.x >= 0) & ((sub & ~C & 7) == 0) &
                     ((unsigned)px < 256u) & ((unsigned)py < 256u) & ((unsigned)pz < 256u);
        int lin = (px >> 1) | ((py >> 1) << 7) | ((pz >> 1) << 14);
        int v = table[valid ? lin : 0];
        res[r] = valid ? v : -1;
    }
    *o0 = res[0]; *o1 = res[1];
}

// stage wt[oi] for admissible rank R into LDS slot (R&3), XOR swizzled
template<int C, int R, int NS>
__device__ __forceinline__ void stage_rank(const unsigned short* __restrict__ wt,
                                           unsigned short* bshr, int mm, int jj) {
    if constexpr (R < NS) {
        constexpr int SUB = nth_sub(C, R);
        constexpr int offx = (C & 1) ? ((SUB & 1) ? 1 : -1) : 0;
        constexpr int offy = (C & 2) ? ((SUB & 2) ? 1 : -1) : 0;
        constexpr int offz = (C & 4) ? ((SUB & 4) ? 1 : -1) : 0;
        constexpr int oi = (offx + 1) * 9 + (offy + 1) * 3 + (offz + 1);
        short8 v = *(const short8*)(wt + oi * 2048 + mm * 64 + jj * 8);
        *(short8*)((char*)bshr + (R & 3) * 4096 + mm * 128 + ((jj ^ (mm & 7)) << 4)) = v;
    }
}

template<int USEFB, int C, int R, int NS>
__device__ __forceinline__ void rank_load(const float* __restrict__ feats,
                                          const unsigned short* __restrict__ fb,
                                          int idx0, int idx1,
                                          unsigned long long bal0, unsigned long long bal1,
                                          int m, int quad, short8* A0, short8* A1) {
    if constexpr (R < NS) {
        constexpr int SUB = nth_sub(C, R);
        unsigned long long bal = (SUB < 4) ? bal0 : bal1;
        unsigned rowm = (unsigned)((bal >> ((SUB & 3) * 16)) & 0xffffull);
        short8 z = {0,0,0,0,0,0,0,0};
        A0[R & 3] = z; A1[R & 3] = z;
        if (rowm) {
            int h = __shfl((SUB < 4) ? idx0 : idx1, (SUB & 3) * 16 + m, 64);
            if (h >= 0) {
                if constexpr (USEFB) {
                    const unsigned short* fp = fb + (size_t)h * NIN + quad * 8;
                    A0[R & 3] = *(const short8*)fp;
                    A1[R & 3] = *(const short8*)(fp + 32);
                } else {
                    const float4* fp = (const float4*)(feats + (size_t)h * NIN + quad * 8);
                    float4 fA = fp[0], fB = fp[1];
                    const float4* fp2 = (const float4*)(feats + (size_t)h * NIN + 32 + quad * 8);
                    float4 fC = fp2[0], fD = fp2[1];
                    short8 x, y;
                    x[0] = (short)bf16rne(fA.x); x[1] = (short)bf16rne(fA.y);
                    x[2] = (short)bf16rne(fA.z); x[3] = (short)bf16rne(fA.w);
                    x[4] = (short)bf16rne(fB.x); x[5] = (short)bf16rne(fB.y);
                    x[6] = (short)bf16rne(fB.z); x[7] = (short)bf16rne(fB.w);
                    y[0] = (short)bf16rne(fC.x); y[1] = (short)bf16rne(fC.y);
                    y[2] = (short)bf16rne(fC.z); y[3] = (short)bf16rne(fC.w);
                    y[4] = (short)bf16rne(fD.x); y[5] = (short)bf16rne(fD.y);
                    y[6] = (short)bf16rne(fD.z); y[7] = (short)bf16rne(fD.w);
                    A0[R & 3] = x; A1[R & 3] = y;
                }
            }
        }
    }
}

// OPERAND-SWAPPED: mfma(W_frag, F_frag) -> acc holds out[g_m][4 consecutive ch].
template<int C, int R, int NS>
__device__ __forceinline__ void rank_mm(const unsigned short* bshr,
                                        unsigned long long bal0, unsigned long long bal1,
                                        int m, int quad, const short8* A0, const short8* A1,
                                        float4v* acc0, float4v* acc1) {
    if constexpr (R < NS) {
        constexpr int SUB = nth_sub(C, R);
        unsigned long long bal = (SUB < 4) ? bal0 : bal1;
        unsigned rowm = (unsigned)((bal >> ((SUB & 3) * 16)) & 0xffffull);
        if (rowm) {
            const char* base = (const char*)bshr + (R & 3) * 4096;
            short8 b00 = *(const short8*)(base + m * 128 + ((quad ^ (m & 7)) << 4));
            short8 b10 = *(const short8*)(base + m * 128 + (((4 + quad) ^ (m & 7)) << 4));
            short8 b01 = *(const short8*)(base + (16 + m) * 128 + ((quad ^ ((16 + m) & 7)) << 4));
            short8 b11 = *(const short8*)(base + (16 + m) * 128 + (((4 + quad) ^ ((16 + m) & 7)) << 4));
            *acc0 = __builtin_amdgcn_mfma_f32_16x16x32_bf16(b00, A0[R & 3], *acc0, 0, 0, 0);
            *acc0 = __builtin_amdgcn_mfma_f32_16x16x32_bf16(b10, A1[R & 3], *acc0, 0, 0, 0);
            *acc1 = __builtin_amdgcn_mfma_f32_16x16x32_bf16(b01, A0[R & 3], *acc1, 0, 0, 0);
            *acc1 = __builtin_amdgcn_mfma_f32_16x16x32_bf16(b11, A1[R & 3], *acc1, 0, 0, 0);
        }
    }
}

template<int USEFB, int C, int P>
__device__ __forceinline__ void phase_tile(const float* __restrict__ feats,
                                           const unsigned short* __restrict__ fb,
                                           const unsigned short* bshr,
                                           int idx0, int idx1,
                                           unsigned long long bal0, unsigned long long bal1,
                                           int m, int quad, float4v* acc0, float4v* acc1) {
    constexpr int NS = 1 << popc8(C);
    short8 A0[4], A1[4];
    rank_load<USEFB, C, P * 4 + 0, NS>(feats, fb, idx0, idx1, bal0, bal1, m, quad, A0, A1);
    rank_load<USEFB, C, P * 4 + 1, NS>(feats, fb, idx0, idx1, bal0, bal1, m, quad, A0, A1);
    rank_load<USEFB, C, P * 4 + 2, NS>(feats, fb, idx0, idx1, bal0, bal1, m, quad, A0, A1);
    rank_load<USEFB, C, P * 4 + 3, NS>(feats, fb, idx0, idx1, bal0, bal1, m, quad, A0, A1);
    rank_mm<C, P * 4 + 0, NS>(bshr, bal0, bal1, m, quad, A0, A1, acc0, acc1);
    rank_mm<C, P * 4 + 1, NS>(bshr, bal0, bal1, m, quad, A0, A1, acc0, acc1);
    rank_mm<C, P * 4 + 2, NS>(bshr, bal0, bal1, m, quad, A0, A1, acc0, acc1);
    rank_mm<C, P * 4 + 3, NS>(bshr, bal0, bal1, m, quad, A0, A1, acc0, acc1);
}

// lane (quad,m): acc0 = out[g_m][quad*4 .. +3], acc1 = out[g_m][16+quad*4 .. +3]
__device__ __forceinline__ void store_tile(int2 s2, unsigned long long eb,
                                           float4v acc0, float4v acc1,
                                           int m, int quad, const float* __restrict__ bias,
                                           float* __restrict__ out) {
    int id = (s2.x < 0) ? -1 : (s2.x & 0xffffff);
    if (id < 0) return;
    unsigned e16 = (unsigned)((eb | (eb >> 16) | (eb >> 32) | (eb >> 48)) & 0xffffull);
    bool ex = (e16 >> m) & 1;
    float4 b0 = ((const float4*)bias)[quad];
    float4 b1 = ((const float4*)bias)[4 + quad];
    float4v v0, v1;
    v0[0] = ex ? (acc0[0] + b0.x) : 0.f;
    v0[1] = ex ? (acc0[1] + b0.y) : 0.f;
    v0[2] = ex ? (acc0[2] + b0.z) : 0.f;
    v0[3] = ex ? (acc0[3] + b0.w) : 0.f;
    v1[0] = ex ? (acc1[0] + b1.x) : 0.f;
    v1[1] = ex ? (acc1[1] + b1.y) : 0.f;
    v1[2] = ex ? (acc1[2] + b1.z) : 0.f;
    v1[3] = ex ? (acc1[3] + b1.w) : 0.f;
    float* op = out + (size_t)id * NOUT;
    *(float4v*)(op + quad * 4)      = v0;
    *(float4v*)(op + 16 + quad * 4) = v1;
}

template<int USEFB, int C>
__device__ __forceinline__ void conv_class(const float* __restrict__ feats,
                                           const unsigned short* __restrict__ fb,
                                           const float* __restrict__ bias,
                                           const int* __restrict__ table,
                                           const int2* __restrict__ sorted,
                                           const unsigned short* __restrict__ wt,
                                           float* __restrict__ out,
                                           int bt0, unsigned short* bshr) {
    constexpr int NS = 1 << popc8(C);
    int tid = threadIdx.x;
    int wid = tid >> 6, lane = tid & 63;
    int m = lane & 15, quad = lane >> 4;

    int t0 = bt0 + wid * 2;
    int2 s2a = sorted[t0 * 16 + m];
    int2 s2b = sorted[t0 * 16 + 16 + m];
    int ia0, ia1, ib0, ib1;
    probe2t<C>(table, s2a, quad, &ia0, &ia1);
    probe2t<C>(table, s2b, quad, &ib0, &ib1);

    {   // stage phase 0 (ranks 0..3) into 16 KB LDS
        int mm = tid >> 3, jj = tid & 7;
        stage_rank<C, 0, NS>(wt, bshr, mm, jj);
        stage_rank<C, 1, NS>(wt, bshr, mm, jj);
        stage_rank<C, 2, NS>(wt, bshr, mm, jj);
        stage_rank<C, 3, NS>(wt, bshr, mm, jj);
    }
    __syncthreads();

    unsigned long long balA0 = __ballot(ia0 >= 0), balA1 = __ballot(ia1 >= 0);
    unsigned long long balB0 = __ballot(ib0 >= 0), balB1 = __ballot(ib1 >= 0);

    float4v aA0 = {0.f,0.f,0.f,0.f}, aA1 = {0.f,0.f,0.f,0.f};
    float4v aB0 = {0.f,0.f,0.f,0.f}, aB1 = {0.f,0.f,0.f,0.f};

    phase_tile<USEFB, C, 0>(feats, fb, bshr, ia0, ia1, balA0, balA1, m, quad, &aA0, &aA1);
    phase_tile<USEFB, C, 0>(feats, fb, bshr, ib0, ib1, balB0, balB1, m, quad, &aB0, &aB1);

    if constexpr (NS > 4) {          // class 7 only: restage ranks 4..7
        __syncthreads();
        {
            int mm = tid >> 3, jj = tid & 7;
            stage_rank<C, 4, NS>(wt, bshr, mm, jj);
            stage_rank<C, 5, NS>(wt, bshr, mm, jj);
            stage_rank<C, 6, NS>(wt, bshr, mm, jj);
            stage_rank<C, 7, NS>(wt, bshr, mm, jj);
        }
        __syncthreads();
        phase_tile<USEFB, C, 1>(feats, fb, bshr, ia0, ia1, balA0, balA1, m, quad, &aA0, &aA1);
        phase_tile<USEFB, C, 1>(feats, fb, bshr, ib0, ib1, balB0, balB1, m, quad, &aB0, &aB1);
    }

    store_tile(s2a, balA0 | balA1, aA0, aA1, m, quad, bias, out);
    store_tile(s2b, balB0 | balB1, aB0, aB1, m, quad, bias, out);
}

template<int USEFB>
__launch_bounds__(256, 6)
__global__ void gen_conv(const float* __restrict__ feats,
                         const unsigned short* __restrict__ fb,
                         const float* __restrict__ bias,
                         const int* __restrict__ table,
                         const int2* __restrict__ sorted,
                         const int* __restrict__ totalp,       // [1]
                         const unsigned short* __restrict__ wt,
                         float* __restrict__ out) {
    __shared__ unsigned short bshr[8192];                      // 16 KB

    int nwg = gridDim.x;
    int orig = blockIdx.x;
    int qd = nwg >> 3, rd = nwg & 7;
    int xc = orig & 7, ix = orig >> 3;
    int wg = (xc < rd ? xc * (qd + 1) : rd * (qd + 1) + (xc - rd) * qd) + ix;

    int g0 = wg * BLKG;
    if (g0 >= totalp[0]) return;       // uniform exit
    // block is inside one (cell,class) bucket; its first entry is always valid
    int c = (sorted[g0].x >> 24) & 7;  // uniform broadcast load
    c = __builtin_amdgcn_readfirstlane(c);
    int bt0 = wg * (BLKG / 16);

    switch (c) {
        case 0: conv_class<USEFB, 0>(feats, fb, bias, table, sorted, wt, out, bt0, bshr); break;
        case 1: conv_class<USEFB, 1>(feats, fb, bias, table, sorted, wt, out, bt0, bshr); break;
        case 2: conv_class<USEFB, 2>(feats, fb, bias, table, sorted, wt, out, bt0, bshr); break;
        case 3: conv_class<USEFB, 3>(feats, fb, bias, table, sorted, wt, out, bt0, bshr); break;
        case 4: conv_class<USEFB, 4>(feats, fb, bias, table, sorted, wt, out, bt0, bshr); break;
        case 5: conv_class<USEFB, 5>(feats, fb, bias, table, sorted, wt, out, bt0, bshr); break;
        case 6: conv_class<USEFB, 6>(feats, fb, bias, table, sorted, wt, out, bt0, bshr); break;
        case 7: conv_class<USEFB, 7>(feats, fb, bias, table, sorted, wt, out, bt0, bshr); break;
    }
}

extern "C" void kernel_launch(void* const* d_in, const int* in_sizes, int n_in,
                              void* d_out, int out_size, void* d_ws, size_t ws_size,
                              hipStream_t stream) {
    const float* feats   = (const float*)d_in[0];
    const float* weights = (const float*)d_in[1];
    const float* bias    = (const float*)d_in[2];
    const int*   coords  = (const int*)d_in[3];
    const int*   guide   = (const int*)d_in[4];
    float* out = (float*)d_out;

    int np = in_sizes[3] / 4;
    int ng = in_sizes[4] / 4;

    int cblocks = (ng + CHUNK - 1) / CHUNK;
    int* wsI = (int*)d_ws;
    int SC = (ng + NB * BLKG + 3) & ~3;      // sorted capacity (worst-case padding)
    int A = TSIZE + 2 * SC;                  // sorted is int2
    int* table     = wsI;                    // 2^21
    int2* sorted   = (int2*)(wsI + TSIZE);   // SC entries, -1 padded
    int* total     = wsI + A;                // 1 (+3 pad)
    int* chunkhist = wsI + A + 4;            // cblocks*NB
    int CH = cblocks * NB;
    unsigned short* wt = (unsigned short*)(wsI + A + 4 + CH);   // 27*32*64 bf16
    unsigned short* fb = (unsigned short*)(wsI + A + 4 + CH + 27648);
    size_t need = ((size_t)A + 4 + CH + 27648) * 4 + (size_t)np * NIN * 2;
    int usefb = (ws_size >= need) ? 1 : 0;

    int n4 = A / 4;
    int fn4 = usefb ? np * (NIN / 4) : 0;
    int prep_n = n4 > fn4 ? n4 : fn4;
    if (prep_n < 27 * 64 * 32) prep_n = 27 * 64 * 32;
    int prep_blocks = (prep_n + 255) / 256;
    if (prep_blocks < cblocks) prep_blocks = cblocks;
    hipLaunchKernelGGL(prep, dim3(prep_blocks), dim3(256), 0, stream,
                       (int4*)wsI, n4, weights, wt, feats, fb, fn4,
                       guide, ng, chunkhist);

    hipLaunchKernelGGL(scanB, dim3(1), dim3(NB), 0, stream, chunkhist, cblocks, total);

    int sb1 = (np + 255) / 256;
    int sblocks = sb1 > cblocks ? sb1 : cblocks;
    hipLaunchKernelGGL(scat, dim3(sblocks), dim3(256), 0, stream,
                       coords, np, table, guide, ng, chunkhist, sorted);

    int maxguides = ng + NB * (BLKG - 1);
    int blocks = (maxguides + BLKG - 1) / BLKG;
    if (usefb) {
        hipLaunchKernelGGL((gen_conv<1>), dim3(blocks), dim3(256), 0, stream,
                           feats, fb, bias, table, sorted, total, wt, out);
    } else {
        hipLaunchKernelGGL((gen_conv<0>), dim3(blocks), dim3(256), 0, stream,
                           feats, fb, bias, table, sorted, total, wt, out);
    }
}